// Round 9
// baseline (612.104 us; speedup 1.0000x reference)
//
#include <hip/hip_runtime.h>
#include <hip/hip_bf16.h>

#define Nn 50000
#define Ee 800000
#define FIN 128
#define HCc 256
#define NH 8
#define HIDc 32
#define NCLS 40
#define NCH ((Nn + 255) / 256)

typedef short s16x8 __attribute__((ext_vector_type(8)));
typedef unsigned short u16x8 __attribute__((ext_vector_type(8)));
typedef unsigned short u16x4 __attribute__((ext_vector_type(4)));
typedef float f32x4 __attribute__((ext_vector_type(4)));
typedef unsigned short ushort_t;

__device__ __forceinline__ ushort_t f2bf(float f) {
    unsigned u = __float_as_uint(f);
    unsigned r = (u + 0x7fffu + ((u >> 16) & 1u)) >> 16;
    return (ushort_t)r;
}
__device__ __forceinline__ float bf2f(ushort_t h) {
    return __uint_as_float(((unsigned)h) << 16);
}

// ---------------- index-width detection (int32 vs int64 edge_index) --------
__global__ void detect_idx_kernel(const unsigned int* __restrict__ ei, int* __restrict__ flag) {
    int t = blockIdx.x * blockDim.x + threadIdx.x;
    if (t < 2048) {
        if (ei[2 * t + 1] != 0u) atomicOr(flag, 1);  // nonzero odd word => int32 data
    }
}

__device__ __forceinline__ int load_idx(const void* ei, long long pos, int is32) {
    return is32 ? ((const int*)ei)[pos] : (int)((const long long*)ei)[pos];
}

// ---------------- CSR build ------------------------------------------------
__global__ void init_deg_kernel(int* __restrict__ deg) {
    int n = blockIdx.x * blockDim.x + threadIdx.x;
    if (n < Nn) deg[n] = 1;  // self loop
}

__global__ void deg_count_kernel(const void* __restrict__ ei, const int* __restrict__ flag,
                                 int* __restrict__ deg) {
    int e = blockIdx.x * blockDim.x + threadIdx.x;
    if (e >= Ee) return;
    int is32 = *flag;
    int d = load_idx(ei, (long long)Ee + e, is32);
    atomicAdd(&deg[d], 1);
}

__global__ __launch_bounds__(256) void scan_k1(const int* __restrict__ deg, int* __restrict__ off,
                                               int* __restrict__ bsum) {
    __shared__ int buf[256];
    int tid = threadIdx.x;
    int idx = blockIdx.x * 256 + tid;
    int v = (idx < Nn) ? deg[idx] : 0;
    buf[tid] = v;
    __syncthreads();
    for (int s = 1; s < 256; s <<= 1) {
        int t = (tid >= s) ? buf[tid - s] : 0;
        __syncthreads();
        buf[tid] += t;
        __syncthreads();
    }
    if (idx < Nn) off[idx + 1] = buf[tid];  // local inclusive; fixed in k3
    if (tid == 255) bsum[blockIdx.x] = buf[255];
}

__global__ __launch_bounds__(256) void scan_k2(const int* __restrict__ bsum, int* __restrict__ boff) {
    __shared__ int buf[256];
    int tid = threadIdx.x;
    int v = (tid < NCH) ? bsum[tid] : 0;
    buf[tid] = v;
    __syncthreads();
    for (int s = 1; s < 256; s <<= 1) {
        int t = (tid >= s) ? buf[tid - s] : 0;
        __syncthreads();
        buf[tid] += t;
        __syncthreads();
    }
    if (tid < NCH) boff[tid] = buf[tid] - v;  // exclusive
}

__global__ void scan_k3(int* __restrict__ off, const int* __restrict__ boff) {
    int idx = blockIdx.x * 256 + threadIdx.x;
    if (idx < Nn) off[idx + 1] += boff[blockIdx.x];
    if (idx == 0) off[0] = 0;
}

__global__ void cursor_init_kernel(const int* __restrict__ off, int* __restrict__ cursor,
                                   int* __restrict__ srcl) {
    int n = blockIdx.x * blockDim.x + threadIdx.x;
    if (n < Nn) {
        int b = off[n];
        srcl[b] = n;        // self loop occupies slot 0
        cursor[n] = b + 1;
    }
}

__global__ void fill_kernel(const void* __restrict__ ei, const int* __restrict__ flag,
                            int* __restrict__ cursor, int* __restrict__ srcl) {
    int e = blockIdx.x * blockDim.x + threadIdx.x;
    if (e >= Ee) return;
    int is32 = *flag;
    int s = load_idx(ei, e, is32);
    int d = load_idx(ei, (long long)Ee + e, is32);
    int slot = atomicAdd(&cursor[d], 1);
    srcl[slot] = s;
}

// ---------------- weight split+transpose: W[K,256] -> Wt_hi/lo[256,K] ------
__global__ void wsplit_kernel(const float* __restrict__ W, int K, ushort_t* __restrict__ Th,
                              ushort_t* __restrict__ Tl) {
    int idx = blockIdx.x * 256 + threadIdx.x;
    if (idx >= K * 256) return;
    int k = idx >> 8, n = idx & 255;
    float v = W[idx];
    ushort_t h = f2bf(v);
    ushort_t l = f2bf(v - bf2f(h));
    Th[n * K + k] = h;
    Tl[n * K + k] = l;
}

// ---------------- split-bf16 MFMA GEMM: C[M,256] = A[M,K] @ B[K,256] -------
// A fp32 (split to hi/lo bf16 during LDS staging); B pre-split+transposed.
// 3-term: Ah*Bh + Ah*Bl + Al*Bh  (error ~2^-16 relative, fp32-equivalent)
#define GBM 128
#define GBN 128
#define GBK 64

__global__ __launch_bounds__(256) void gemm_mfma_kernel(const float* __restrict__ A,
                                                        const ushort_t* __restrict__ BtH,
                                                        const ushort_t* __restrict__ BtL,
                                                        float* __restrict__ C, int M, int K) {
    __shared__ __align__(16) ushort_t AhS[GBM * GBK];
    __shared__ __align__(16) ushort_t AlS[GBM * GBK];
    __shared__ __align__(16) ushort_t BhS[GBN * GBK];
    __shared__ __align__(16) ushort_t BlS[GBN * GBK];
    int tid = threadIdx.x;
    int lane = tid & 63, wid = tid >> 6;
    int wm = wid >> 1, wn = wid & 1;  // 2x2 wave grid, each wave: 64x64 output
    int row0 = blockIdx.y * GBM, col0 = blockIdx.x * GBN;
    f32x4 acc[4][4] = {};
    for (int k0 = 0; k0 < K; k0 += GBK) {
        // stage A: fp32 -> (hi,lo) bf16, XOR-swizzled
        #pragma unroll
        for (int i = 0; i < 8; i++) {
            int q = tid + i * 256;
            int r = q >> 4, c4 = (q & 15) * 4;
            float4 v = make_float4(0.f, 0.f, 0.f, 0.f);
            int gr = row0 + r;
            if (gr < M) v = *(const float4*)(A + (size_t)gr * K + k0 + c4);
            ushort_t h0 = f2bf(v.x), h1 = f2bf(v.y), h2 = f2bf(v.z), h3 = f2bf(v.w);
            u16x4 hv = {h0, h1, h2, h3};
            u16x4 lv = {f2bf(v.x - bf2f(h0)), f2bf(v.y - bf2f(h1)), f2bf(v.z - bf2f(h2)),
                        f2bf(v.w - bf2f(h3))};
            int idx = (r * GBK + c4) ^ ((r & 7) << 3);
            *(u16x4*)&AhS[idx] = hv;
            *(u16x4*)&AlS[idx] = lv;
        }
        // stage B: pre-split bf16, 16B loads, XOR-swizzled
        #pragma unroll
        for (int i = 0; i < 4; i++) {
            int q = tid + i * 256;
            int r = q >> 3, c8 = (q & 7) * 8;
            size_t gofs = (size_t)(col0 + r) * K + k0 + c8;
            int idx = (r * GBK + c8) ^ ((r & 7) << 3);
            *(u16x8*)&BhS[idx] = *(const u16x8*)(BtH + gofs);
            *(u16x8*)&BlS[idx] = *(const u16x8*)(BtL + gofs);
        }
        __syncthreads();
        #pragma unroll
        for (int kk = 0; kk < GBK; kk += 32) {
            s16x8 ah[4], al[4], bh[4], bl[4];
            int kb = kk + (lane >> 4) * 8;
            #pragma unroll
            for (int f = 0; f < 4; f++) {
                int ra = wm * 64 + f * 16 + (lane & 15);
                int ia = (ra * GBK + kb) ^ ((ra & 7) << 3);
                ah[f] = *(const s16x8*)&AhS[ia];
                al[f] = *(const s16x8*)&AlS[ia];
                int rb = wn * 64 + f * 16 + (lane & 15);
                int ib = (rb * GBK + kb) ^ ((rb & 7) << 3);
                bh[f] = *(const s16x8*)&BhS[ib];
                bl[f] = *(const s16x8*)&BlS[ib];
            }
            #pragma unroll
            for (int fm = 0; fm < 4; fm++)
                #pragma unroll
                for (int fn = 0; fn < 4; fn++) {
                    acc[fm][fn] =
                        __builtin_amdgcn_mfma_f32_16x16x32_bf16(ah[fm], bh[fn], acc[fm][fn], 0, 0, 0);
                    acc[fm][fn] =
                        __builtin_amdgcn_mfma_f32_16x16x32_bf16(ah[fm], bl[fn], acc[fm][fn], 0, 0, 0);
                    acc[fm][fn] =
                        __builtin_amdgcn_mfma_f32_16x16x32_bf16(al[fm], bh[fn], acc[fm][fn], 0, 0, 0);
                }
        }
        __syncthreads();
    }
    // epilogue: C layout col=lane&15, row=(lane>>4)*4+j
    #pragma unroll
    for (int fm = 0; fm < 4; fm++) {
        int r0 = row0 + wm * 64 + fm * 16 + (lane >> 4) * 4;
        #pragma unroll
        for (int fn = 0; fn < 4; fn++) {
            int c = col0 + wn * 64 + fn * 16 + (lane & 15);
            #pragma unroll
            for (int j = 0; j < 4; j++) {
                int gr = r0 + j;
                if (gr < M) C[(size_t)gr * HCc + c] = acc[fm][fn][j];
            }
        }
    }
}

// ---------------- per-node attention scalars a_s, a_d ----------------------
__global__ void att_kernel(const float* __restrict__ h, const float* __restrict__ att_s,
                           const float* __restrict__ att_d, float* __restrict__ asv,
                           float* __restrict__ adv) {
    int t = blockIdx.x * blockDim.x + threadIdx.x;
    if (t >= Nn * NH) return;
    int n = t >> 3, hh = t & 7;
    const float4* hp = (const float4*)(h + (size_t)n * HCc + hh * HIDc);
    const float4* sp = (const float4*)(att_s + hh * HIDc);
    const float4* dp = (const float4*)(att_d + hh * HIDc);
    float s = 0.f, d = 0.f;
    #pragma unroll
    for (int c = 0; c < 8; c++) {
        float4 v = hp[c], a = sp[c], b = dp[c];
        s += v.x * a.x + v.y * a.y + v.z * a.z + v.w * a.w;
        d += v.x * b.x + v.y * b.y + v.z * b.z + v.w * b.w;
    }
    asv[t] = s;
    adv[t] = d;
}

// ---------------- per-dst-node softmax + weighted aggregation --------------
// one wave per dst node; no max pass (softmax shift-invariant, |e|<~10 here).
// Fast path (deg<=64, ~always at mean deg 17): src indices staged in LDS,
// exp weights cached in LDS, row-gather unrolled x4 for 4 loads in flight.
__global__ __launch_bounds__(256) void aggregate_kernel(
    const float* __restrict__ h, const float* __restrict__ asv, const float* __restrict__ adv,
    const int* __restrict__ off, const int* __restrict__ srcl, const float* __restrict__ bias,
    float* __restrict__ out, int elu) {
    __shared__ float wbuf[4][512];  // 4 waves x 64 edges x 8 heads
    __shared__ int sbuf[4][64];     // 4 waves x 64 src indices
    int wave = threadIdx.x >> 6;
    int lane = threadIdx.x & 63;
    int n = blockIdx.x * 4 + wave;
    if (n >= Nn) return;
    int base = off[n];
    int deg = off[n + 1] - base;
    int ha = lane & 7;
    float adha = adv[n * NH + ha];
    float* wb = wbuf[wave];
    int* si = sbuf[wave];
    float ssum = 0.f;
    bool fast = (deg <= 64);
    if (fast) {
        if (lane < deg) si[lane] = srcl[base + lane];
        for (int p = lane; p < deg * NH; p += 64) {
            int s = si[p >> 3];
            float e = asv[s * NH + ha] + adha;
            e = (e >= 0.f) ? e : 0.2f * e;
            float ex = __expf(e);
            wb[p] = ex;
            ssum += ex;
        }
    } else {
        for (int p = lane; p < deg * NH; p += 64) {
            int s = srcl[base + (p >> 3)];
            float e = asv[s * NH + ha] + adha;
            e = (e >= 0.f) ? e : 0.2f * e;
            ssum += __expf(e);
        }
    }
    #pragma unroll
    for (int d = 8; d < 64; d <<= 1) ssum += __shfl_xor(ssum, d);
    float inv = 1.f / (ssum + 1e-16f);
    int hc = lane >> 3;
    float invc = __shfl(inv, hc);
    float4 acc = make_float4(0.f, 0.f, 0.f, 0.f);
    if (fast) {
        int i = 0;
        for (; i + 4 <= deg; i += 4) {
            // 4 independent 1KB row loads in flight per wave
            int s0 = si[i + 0], s1 = si[i + 1], s2 = si[i + 2], s3 = si[i + 3];
            float4 v0 = *(const float4*)(h + (size_t)s0 * HCc + lane * 4);
            float4 v1 = *(const float4*)(h + (size_t)s1 * HCc + lane * 4);
            float4 v2 = *(const float4*)(h + (size_t)s2 * HCc + lane * 4);
            float4 v3 = *(const float4*)(h + (size_t)s3 * HCc + lane * 4);
            float w0 = wb[(i + 0) * NH + hc] * invc;
            float w1 = wb[(i + 1) * NH + hc] * invc;
            float w2 = wb[(i + 2) * NH + hc] * invc;
            float w3 = wb[(i + 3) * NH + hc] * invc;
            acc.x += w0 * v0.x + w1 * v1.x + w2 * v2.x + w3 * v3.x;
            acc.y += w0 * v0.y + w1 * v1.y + w2 * v2.y + w3 * v3.y;
            acc.z += w0 * v0.z + w1 * v1.z + w2 * v2.z + w3 * v3.z;
            acc.w += w0 * v0.w + w1 * v1.w + w2 * v2.w + w3 * v3.w;
        }
        for (; i < deg; i++) {
            int s = si[i];
            float w = wb[i * NH + hc] * invc;
            float4 hv = *(const float4*)(h + (size_t)s * HCc + lane * 4);
            acc.x += w * hv.x;
            acc.y += w * hv.y;
            acc.z += w * hv.z;
            acc.w += w * hv.w;
        }
    } else {
        float adhc = adv[n * NH + hc];
        for (int i = 0; i < deg; i++) {
            int s = srcl[base + i];
            float e = asv[s * NH + hc] + adhc;
            e = (e >= 0.f) ? e : 0.2f * e;
            float w = __expf(e) * invc;
            float4 hv = *(const float4*)(h + (size_t)s * HCc + lane * 4);
            acc.x += w * hv.x;
            acc.y += w * hv.y;
            acc.z += w * hv.z;
            acc.w += w * hv.w;
        }
    }
    float4 bv = *(const float4*)(bias + lane * 4);
    acc.x += bv.x;
    acc.y += bv.y;
    acc.z += bv.z;
    acc.w += bv.w;
    if (elu) {
        acc.x = (acc.x > 0.f) ? acc.x : expm1f(acc.x);
        acc.y = (acc.y > 0.f) ? acc.y : expm1f(acc.y);
        acc.z = (acc.z > 0.f) ? acc.z : expm1f(acc.z);
        acc.w = (acc.w > 0.f) ? acc.w : expm1f(acc.w);
    }
    *(float4*)(out + (size_t)n * HCc + lane * 4) = acc;
}

// ---------------- classifier: out[N,40] = h[N,256] @ wc[256,40] + bc -------
__global__ __launch_bounds__(256) void classifier_kernel(const float* __restrict__ h,
                                                         const float* __restrict__ wc,
                                                         const float* __restrict__ bc,
                                                         float* __restrict__ out) {
    __shared__ float hs[32][260];
    __shared__ float wcs[HCc * NCLS];
    int tid = threadIdx.x;
    int row0 = blockIdx.x * 32;
    #pragma unroll
    for (int i = 0; i < 8; i++) {
        int f = tid + i * 256;
        int r = f >> 6, c = (f & 63) * 4;
        float4 v = make_float4(0.f, 0.f, 0.f, 0.f);
        int gr = row0 + r;
        if (gr < Nn) v = *(const float4*)(h + (size_t)gr * HCc + c);
        *(float4*)&hs[r][c] = v;
    }
    #pragma unroll
    for (int i = 0; i < 10; i++) {
        int f = (tid + i * 256) * 4;
        *(float4*)&wcs[f] = *(const float4*)(wc + f);
    }
    __syncthreads();
    int r = tid >> 3, cg = tid & 7;
    int gr = row0 + r;
    if (gr >= Nn) return;
    float acc[5] = {0.f, 0.f, 0.f, 0.f, 0.f};
    for (int k = 0; k < HCc; k++) {
        float hv = hs[r][k];
        const float* w = &wcs[k * NCLS + cg * 5];
        #pragma unroll
        for (int j = 0; j < 5; j++) acc[j] += hv * w[j];
    }
    #pragma unroll
    for (int j = 0; j < 5; j++) out[(size_t)gr * NCLS + cg * 5 + j] = acc[j] + bc[cg * 5 + j];
}

// ---------------- launch ---------------------------------------------------
extern "C" void kernel_launch(void* const* d_in, const int* in_sizes, int n_in, void* d_out,
                              int out_size, void* d_ws, size_t ws_size, hipStream_t stream) {
    const float* x   = (const float*)d_in[0];
    const void*  ei  = d_in[1];
    const float* w1  = (const float*)d_in[2];
    const float* as1 = (const float*)d_in[3];
    const float* ad1 = (const float*)d_in[4];
    const float* b1  = (const float*)d_in[5];
    const float* w2  = (const float*)d_in[6];
    const float* as2 = (const float*)d_in[7];
    const float* ad2 = (const float*)d_in[8];
    const float* b2  = (const float*)d_in[9];
    const float* wc  = (const float*)d_in[10];
    const float* bc  = (const float*)d_in[11];
    float* out = (float*)d_out;

    char* p = (char*)d_ws;
    auto alloc = [&](size_t bytes) -> void* {
        void* r = (void*)p;
        p += (bytes + 255) & ~(size_t)255;
        return r;
    };
    float* h     = (float*)alloc((size_t)Nn * HCc * 4);
    float* t1    = (float*)alloc((size_t)Nn * HCc * 4);
    float* asv   = (float*)alloc((size_t)Nn * NH * 4);
    float* adv   = (float*)alloc((size_t)Nn * NH * 4);
    int* off     = (int*)alloc((Nn + 1) * 4);
    int* deg     = (int*)alloc(Nn * 4);
    int* cursor  = (int*)alloc(Nn * 4);
    int* bsum    = (int*)alloc(NCH * 4);
    int* boff    = (int*)alloc(NCH * 4);
    int* srcl    = (int*)alloc((size_t)(Ee + Nn) * 4);
    int* flag    = (int*)alloc(4);
    ushort_t* w1th = (ushort_t*)alloc((size_t)FIN * HCc * 2);
    ushort_t* w1tl = (ushort_t*)alloc((size_t)FIN * HCc * 2);
    ushort_t* w2th = (ushort_t*)alloc((size_t)HCc * HCc * 2);
    ushort_t* w2tl = (ushort_t*)alloc((size_t)HCc * HCc * 2);

    hipMemsetAsync(flag, 0, 4, stream);
    detect_idx_kernel<<<8, 256, 0, stream>>>((const unsigned int*)ei, flag);
    init_deg_kernel<<<(Nn + 255) / 256, 256, 0, stream>>>(deg);
    deg_count_kernel<<<(Ee + 255) / 256, 256, 0, stream>>>(ei, flag, deg);
    scan_k1<<<NCH, 256, 0, stream>>>(deg, off, bsum);
    scan_k2<<<1, 256, 0, stream>>>(bsum, boff);
    scan_k3<<<NCH, 256, 0, stream>>>(off, boff);
    cursor_init_kernel<<<(Nn + 255) / 256, 256, 0, stream>>>(off, cursor, srcl);
    fill_kernel<<<(Ee + 255) / 256, 256, 0, stream>>>(ei, flag, cursor, srcl);
    wsplit_kernel<<<(FIN * HCc + 255) / 256, 256, 0, stream>>>(w1, FIN, w1th, w1tl);
    wsplit_kernel<<<(HCc * HCc + 255) / 256, 256, 0, stream>>>(w2, HCc, w2th, w2tl);

    // layer 1
    gemm_mfma_kernel<<<dim3(2, (Nn + GBM - 1) / GBM), 256, 0, stream>>>(x, w1th, w1tl, h, Nn, FIN);
    att_kernel<<<(Nn * NH + 255) / 256, 256, 0, stream>>>(h, as1, ad1, asv, adv);
    aggregate_kernel<<<(Nn + 3) / 4, 256, 0, stream>>>(h, asv, adv, off, srcl, b1, t1, 1);
    // layer 2
    gemm_mfma_kernel<<<dim3(2, (Nn + GBM - 1) / GBM), 256, 0, stream>>>(t1, w2th, w2tl, h, Nn, HCc);
    att_kernel<<<(Nn * NH + 255) / 256, 256, 0, stream>>>(h, as2, ad2, asv, adv);
    aggregate_kernel<<<(Nn + 3) / 4, 256, 0, stream>>>(h, asv, adv, off, srcl, b2, t1, 0);
    // classifier
    classifier_kernel<<<(Nn + 31) / 32, 256, 0, stream>>>(t1, wc, bc, out);
}

// Round 11
// 496.490 us; speedup vs baseline: 1.2329x; 1.2329x over previous
//
#include <hip/hip_runtime.h>
#include <hip/hip_bf16.h>

#define Nn 50000
#define Ee 800000
#define FIN 128
#define HCc 256
#define NH 8
#define HIDc 32
#define NCLS 40
#define NCH ((Nn + 255) / 256)

typedef short s16x8 __attribute__((ext_vector_type(8)));
typedef unsigned short u16x8 __attribute__((ext_vector_type(8)));
typedef unsigned short u16x4 __attribute__((ext_vector_type(4)));
typedef float f32x4 __attribute__((ext_vector_type(4)));
typedef unsigned short ushort_t;

__device__ __forceinline__ ushort_t f2bf(float f) {
    unsigned u = __float_as_uint(f);
    unsigned r = (u + 0x7fffu + ((u >> 16) & 1u)) >> 16;
    return (ushort_t)r;
}
__device__ __forceinline__ float bf2f(ushort_t h) {
    return __uint_as_float(((unsigned)h) << 16);
}

// ---------------- index-width detection (int32 vs int64 edge_index) --------
__global__ void detect_idx_kernel(const unsigned int* __restrict__ ei, int* __restrict__ flag) {
    int t = blockIdx.x * blockDim.x + threadIdx.x;
    if (t < 2048) {
        if (ei[2 * t + 1] != 0u) atomicOr(flag, 1);  // nonzero odd word => int32 data
    }
}

__device__ __forceinline__ int load_idx(const void* ei, long long pos, int is32) {
    return is32 ? ((const int*)ei)[pos] : (int)((const long long*)ei)[pos];
}

// ---------------- CSR build ------------------------------------------------
__global__ void init_deg_kernel(int* __restrict__ deg) {
    int n = blockIdx.x * blockDim.x + threadIdx.x;
    if (n < Nn) deg[n] = 1;  // self loop
}

__global__ void deg_count_kernel(const void* __restrict__ ei, const int* __restrict__ flag,
                                 int* __restrict__ deg) {
    int e = blockIdx.x * blockDim.x + threadIdx.x;
    if (e >= Ee) return;
    int is32 = *flag;
    int d = load_idx(ei, (long long)Ee + e, is32);
    atomicAdd(&deg[d], 1);
}

__global__ __launch_bounds__(256) void scan_k1(const int* __restrict__ deg, int* __restrict__ off,
                                               int* __restrict__ bsum) {
    __shared__ int buf[256];
    int tid = threadIdx.x;
    int idx = blockIdx.x * 256 + tid;
    int v = (idx < Nn) ? deg[idx] : 0;
    buf[tid] = v;
    __syncthreads();
    for (int s = 1; s < 256; s <<= 1) {
        int t = (tid >= s) ? buf[tid - s] : 0;
        __syncthreads();
        buf[tid] += t;
        __syncthreads();
    }
    if (idx < Nn) off[idx + 1] = buf[tid];  // local inclusive; fixed in k3
    if (tid == 255) bsum[blockIdx.x] = buf[255];
}

__global__ __launch_bounds__(256) void scan_k2(const int* __restrict__ bsum, int* __restrict__ boff) {
    __shared__ int buf[256];
    int tid = threadIdx.x;
    int v = (tid < NCH) ? bsum[tid] : 0;
    buf[tid] = v;
    __syncthreads();
    for (int s = 1; s < 256; s <<= 1) {
        int t = (tid >= s) ? buf[tid - s] : 0;
        __syncthreads();
        buf[tid] += t;
        __syncthreads();
    }
    if (tid < NCH) boff[tid] = buf[tid] - v;  // exclusive
}

__global__ void scan_k3(int* __restrict__ off, const int* __restrict__ boff) {
    int idx = blockIdx.x * 256 + threadIdx.x;
    if (idx < Nn) off[idx + 1] += boff[blockIdx.x];
    if (idx == 0) off[0] = 0;
}

__global__ void cursor_init_kernel(const int* __restrict__ off, int* __restrict__ cursor,
                                   int* __restrict__ srcl) {
    int n = blockIdx.x * blockDim.x + threadIdx.x;
    if (n < Nn) {
        int b = off[n];
        srcl[b] = n;        // self loop occupies slot 0
        cursor[n] = b + 1;
    }
}

__global__ void fill_kernel(const void* __restrict__ ei, const int* __restrict__ flag,
                            int* __restrict__ cursor, int* __restrict__ srcl) {
    int e = blockIdx.x * blockDim.x + threadIdx.x;
    if (e >= Ee) return;
    int is32 = *flag;
    int s = load_idx(ei, e, is32);
    int d = load_idx(ei, (long long)Ee + e, is32);
    int slot = atomicAdd(&cursor[d], 1);
    srcl[slot] = s;
}

// ---------------- weight split+transpose: W[K,256] -> Wt_hi/lo[256,K] ------
__global__ void wsplit_kernel(const float* __restrict__ W, int K, ushort_t* __restrict__ Th,
                              ushort_t* __restrict__ Tl) {
    int idx = blockIdx.x * 256 + threadIdx.x;
    if (idx >= K * 256) return;
    int k = idx >> 8, n = idx & 255;
    float v = W[idx];
    ushort_t h = f2bf(v);
    ushort_t l = f2bf(v - bf2f(h));
    Th[n * K + k] = h;
    Tl[n * K + k] = l;
}

// ---------------- split-bf16 MFMA GEMM: C[M,256] = A[M,K] @ B[K,256] -------
// A fp32 (split to hi/lo bf16 during LDS staging); B pre-split+transposed.
// 3-term: Ah*Bh + Ah*Bl + Al*Bh  (error ~2^-16 relative, fp32-equivalent)
// Epilogue also writes a bf16 shadow copy Cb (gather operand for aggregate).
#define GBM 128
#define GBN 128
#define GBK 64

__global__ __launch_bounds__(256) void gemm_mfma_kernel(const float* __restrict__ A,
                                                        const ushort_t* __restrict__ BtH,
                                                        const ushort_t* __restrict__ BtL,
                                                        float* __restrict__ C,
                                                        ushort_t* __restrict__ Cb, int M, int K) {
    __shared__ __align__(16) ushort_t AhS[GBM * GBK];
    __shared__ __align__(16) ushort_t AlS[GBM * GBK];
    __shared__ __align__(16) ushort_t BhS[GBN * GBK];
    __shared__ __align__(16) ushort_t BlS[GBN * GBK];
    int tid = threadIdx.x;
    int lane = tid & 63, wid = tid >> 6;
    int wm = wid >> 1, wn = wid & 1;  // 2x2 wave grid, each wave: 64x64 output
    int row0 = blockIdx.y * GBM, col0 = blockIdx.x * GBN;
    f32x4 acc[4][4] = {};
    for (int k0 = 0; k0 < K; k0 += GBK) {
        // stage A: fp32 -> (hi,lo) bf16, XOR-swizzled
        #pragma unroll
        for (int i = 0; i < 8; i++) {
            int q = tid + i * 256;
            int r = q >> 4, c4 = (q & 15) * 4;
            float4 v = make_float4(0.f, 0.f, 0.f, 0.f);
            int gr = row0 + r;
            if (gr < M) v = *(const float4*)(A + (size_t)gr * K + k0 + c4);
            ushort_t h0 = f2bf(v.x), h1 = f2bf(v.y), h2 = f2bf(v.z), h3 = f2bf(v.w);
            u16x4 hv = {h0, h1, h2, h3};
            u16x4 lv = {f2bf(v.x - bf2f(h0)), f2bf(v.y - bf2f(h1)), f2bf(v.z - bf2f(h2)),
                        f2bf(v.w - bf2f(h3))};
            int idx = (r * GBK + c4) ^ ((r & 7) << 3);
            *(u16x4*)&AhS[idx] = hv;
            *(u16x4*)&AlS[idx] = lv;
        }
        // stage B: pre-split bf16, 16B loads, XOR-swizzled
        #pragma unroll
        for (int i = 0; i < 4; i++) {
            int q = tid + i * 256;
            int r = q >> 3, c8 = (q & 7) * 8;
            size_t gofs = (size_t)(col0 + r) * K + k0 + c8;
            int idx = (r * GBK + c8) ^ ((r & 7) << 3);
            *(u16x8*)&BhS[idx] = *(const u16x8*)(BtH + gofs);
            *(u16x8*)&BlS[idx] = *(const u16x8*)(BtL + gofs);
        }
        __syncthreads();
        #pragma unroll
        for (int kk = 0; kk < GBK; kk += 32) {
            s16x8 ah[4], al[4], bh[4], bl[4];
            int kb = kk + (lane >> 4) * 8;
            #pragma unroll
            for (int f = 0; f < 4; f++) {
                int ra = wm * 64 + f * 16 + (lane & 15);
                int ia = (ra * GBK + kb) ^ ((ra & 7) << 3);
                ah[f] = *(const s16x8*)&AhS[ia];
                al[f] = *(const s16x8*)&AlS[ia];
                int rb = wn * 64 + f * 16 + (lane & 15);
                int ib = (rb * GBK + kb) ^ ((rb & 7) << 3);
                bh[f] = *(const s16x8*)&BhS[ib];
                bl[f] = *(const s16x8*)&BlS[ib];
            }
            #pragma unroll
            for (int fm = 0; fm < 4; fm++)
                #pragma unroll
                for (int fn = 0; fn < 4; fn++) {
                    acc[fm][fn] =
                        __builtin_amdgcn_mfma_f32_16x16x32_bf16(ah[fm], bh[fn], acc[fm][fn], 0, 0, 0);
                    acc[fm][fn] =
                        __builtin_amdgcn_mfma_f32_16x16x32_bf16(ah[fm], bl[fn], acc[fm][fn], 0, 0, 0);
                    acc[fm][fn] =
                        __builtin_amdgcn_mfma_f32_16x16x32_bf16(al[fm], bh[fn], acc[fm][fn], 0, 0, 0);
                }
        }
        __syncthreads();
    }
    // epilogue: C layout col=lane&15, row=(lane>>4)*4+j ; also bf16 shadow
    #pragma unroll
    for (int fm = 0; fm < 4; fm++) {
        int r0 = row0 + wm * 64 + fm * 16 + (lane >> 4) * 4;
        #pragma unroll
        for (int fn = 0; fn < 4; fn++) {
            int c = col0 + wn * 64 + fn * 16 + (lane & 15);
            #pragma unroll
            for (int j = 0; j < 4; j++) {
                int gr = r0 + j;
                if (gr < M) {
                    float v = acc[fm][fn][j];
                    C[(size_t)gr * HCc + c] = v;
                    Cb[(size_t)gr * HCc + c] = f2bf(v);
                }
            }
        }
    }
}

// ---------------- per-node attention scalars a_s, a_d ----------------------
__global__ void att_kernel(const float* __restrict__ h, const float* __restrict__ att_s,
                           const float* __restrict__ att_d, float* __restrict__ asv,
                           float* __restrict__ adv) {
    int t = blockIdx.x * blockDim.x + threadIdx.x;
    if (t >= Nn * NH) return;
    int n = t >> 3, hh = t & 7;
    const float4* hp = (const float4*)(h + (size_t)n * HCc + hh * HIDc);
    const float4* sp = (const float4*)(att_s + hh * HIDc);
    const float4* dp = (const float4*)(att_d + hh * HIDc);
    float s = 0.f, d = 0.f;
    #pragma unroll
    for (int c = 0; c < 8; c++) {
        float4 v = hp[c], a = sp[c], b = dp[c];
        s += v.x * a.x + v.y * a.y + v.z * a.z + v.w * a.w;
        d += v.x * b.x + v.y * b.y + v.z * b.z + v.w * b.w;
    }
    asv[t] = s;
    adv[t] = d;
}

// ---------------- per-dst-node softmax + weighted aggregation --------------
// one wave per dst node; no max pass (softmax shift-invariant, |e|<~10 here).
// Gather operand is bf16 (hb): halves L2-miss-path bytes (the measured
// bottleneck: ~3.5-3.9 TB/s on random 1KB rows, R4/R9). Accumulate fp32.
__global__ __launch_bounds__(256) void aggregate_kernel(
    const ushort_t* __restrict__ hb, const float* __restrict__ asv, const float* __restrict__ adv,
    const int* __restrict__ off, const int* __restrict__ srcl, const float* __restrict__ bias,
    float* __restrict__ out, int elu) {
    __shared__ float wbuf[4][512];  // 4 waves x 64 edges x 8 heads
    __shared__ int sbuf[4][64];     // 4 waves x 64 src indices
    int wave = threadIdx.x >> 6;
    int lane = threadIdx.x & 63;
    int n = blockIdx.x * 4 + wave;
    if (n >= Nn) return;
    int base = off[n];
    int deg = off[n + 1] - base;
    int ha = lane & 7;
    float adha = adv[n * NH + ha];
    float* wb = wbuf[wave];
    int* si = sbuf[wave];
    float ssum = 0.f;
    bool fast = (deg <= 64);
    if (fast) {
        if (lane < deg) si[lane] = srcl[base + lane];
        for (int p = lane; p < deg * NH; p += 64) {
            int s = si[p >> 3];
            float e = asv[s * NH + ha] + adha;
            e = (e >= 0.f) ? e : 0.2f * e;
            float ex = __expf(e);
            wb[p] = ex;
            ssum += ex;
        }
    } else {
        for (int p = lane; p < deg * NH; p += 64) {
            int s = srcl[base + (p >> 3)];
            float e = asv[s * NH + ha] + adha;
            e = (e >= 0.f) ? e : 0.2f * e;
            ssum += __expf(e);
        }
    }
    #pragma unroll
    for (int d = 8; d < 64; d <<= 1) ssum += __shfl_xor(ssum, d);
    float inv = 1.f / (ssum + 1e-16f);
    int hc = lane >> 3;
    float invc = __shfl(inv, hc);
    float4 acc = make_float4(0.f, 0.f, 0.f, 0.f);
    if (fast) {
        int i = 0;
        for (; i + 4 <= deg; i += 4) {
            // 4 independent 512B row loads in flight per wave
            int s0 = si[i + 0], s1 = si[i + 1], s2 = si[i + 2], s3 = si[i + 3];
            u16x4 b0 = *(const u16x4*)(hb + (size_t)s0 * HCc + lane * 4);
            u16x4 b1 = *(const u16x4*)(hb + (size_t)s1 * HCc + lane * 4);
            u16x4 b2 = *(const u16x4*)(hb + (size_t)s2 * HCc + lane * 4);
            u16x4 b3 = *(const u16x4*)(hb + (size_t)s3 * HCc + lane * 4);
            float w0 = wb[(i + 0) * NH + hc] * invc;
            float w1 = wb[(i + 1) * NH + hc] * invc;
            float w2 = wb[(i + 2) * NH + hc] * invc;
            float w3 = wb[(i + 3) * NH + hc] * invc;
            acc.x += w0 * bf2f(b0[0]) + w1 * bf2f(b1[0]) + w2 * bf2f(b2[0]) + w3 * bf2f(b3[0]);
            acc.y += w0 * bf2f(b0[1]) + w1 * bf2f(b1[1]) + w2 * bf2f(b2[1]) + w3 * bf2f(b3[1]);
            acc.z += w0 * bf2f(b0[2]) + w1 * bf2f(b1[2]) + w2 * bf2f(b2[2]) + w3 * bf2f(b3[2]);
            acc.w += w0 * bf2f(b0[3]) + w1 * bf2f(b1[3]) + w2 * bf2f(b2[3]) + w3 * bf2f(b3[3]);
        }
        for (; i < deg; i++) {
            int s = si[i];
            float w = wb[i * NH + hc] * invc;
            u16x4 bv4 = *(const u16x4*)(hb + (size_t)s * HCc + lane * 4);
            acc.x += w * bf2f(bv4[0]);
            acc.y += w * bf2f(bv4[1]);
            acc.z += w * bf2f(bv4[2]);
            acc.w += w * bf2f(bv4[3]);
        }
    } else {
        float adhc = adv[n * NH + hc];
        for (int i = 0; i < deg; i++) {
            int s = srcl[base + i];
            float e = asv[s * NH + hc] + adhc;
            e = (e >= 0.f) ? e : 0.2f * e;
            float w = __expf(e) * invc;
            u16x4 bv4 = *(const u16x4*)(hb + (size_t)s * HCc + lane * 4);
            acc.x += w * bf2f(bv4[0]);
            acc.y += w * bf2f(bv4[1]);
            acc.z += w * bf2f(bv4[2]);
            acc.w += w * bf2f(bv4[3]);
        }
    }
    float4 bv = *(const float4*)(bias + lane * 4);
    acc.x += bv.x;
    acc.y += bv.y;
    acc.z += bv.z;
    acc.w += bv.w;
    if (elu) {
        acc.x = (acc.x > 0.f) ? acc.x : expm1f(acc.x);
        acc.y = (acc.y > 0.f) ? acc.y : expm1f(acc.y);
        acc.z = (acc.z > 0.f) ? acc.z : expm1f(acc.z);
        acc.w = (acc.w > 0.f) ? acc.w : expm1f(acc.w);
    }
    *(float4*)(out + (size_t)n * HCc + lane * 4) = acc;
}

// ---------------- classifier: out[N,40] = h[N,256] @ wc[256,40] + bc -------
__global__ __launch_bounds__(256) void classifier_kernel(const float* __restrict__ h,
                                                         const float* __restrict__ wc,
                                                         const float* __restrict__ bc,
                                                         float* __restrict__ out) {
    __shared__ float hs[32][260];
    __shared__ float wcs[HCc * NCLS];
    int tid = threadIdx.x;
    int row0 = blockIdx.x * 32;
    #pragma unroll
    for (int i = 0; i < 8; i++) {
        int f = tid + i * 256;
        int r = f >> 6, c = (f & 63) * 4;
        float4 v = make_float4(0.f, 0.f, 0.f, 0.f);
        int gr = row0 + r;
        if (gr < Nn) v = *(const float4*)(h + (size_t)gr * HCc + c);
        *(float4*)&hs[r][c] = v;
    }
    #pragma unroll
    for (int i = 0; i < 10; i++) {
        int f = (tid + i * 256) * 4;
        *(float4*)&wcs[f] = *(const float4*)(wc + f);
    }
    __syncthreads();
    int r = tid >> 3, cg = tid & 7;
    int gr = row0 + r;
    if (gr >= Nn) return;
    float acc[5] = {0.f, 0.f, 0.f, 0.f, 0.f};
    for (int k = 0; k < HCc; k++) {
        float hv = hs[r][k];
        const float* w = &wcs[k * NCLS + cg * 5];
        #pragma unroll
        for (int j = 0; j < 5; j++) acc[j] += hv * w[j];
    }
    #pragma unroll
    for (int j = 0; j < 5; j++) out[(size_t)gr * NCLS + cg * 5 + j] = acc[j] + bc[cg * 5 + j];
}

// ---------------- launch ---------------------------------------------------
extern "C" void kernel_launch(void* const* d_in, const int* in_sizes, int n_in, void* d_out,
                              int out_size, void* d_ws, size_t ws_size, hipStream_t stream) {
    const float* x   = (const float*)d_in[0];
    const void*  ei  = d_in[1];
    const float* w1  = (const float*)d_in[2];
    const float* as1 = (const float*)d_in[3];
    const float* ad1 = (const float*)d_in[4];
    const float* b1  = (const float*)d_in[5];
    const float* w2  = (const float*)d_in[6];
    const float* as2 = (const float*)d_in[7];
    const float* ad2 = (const float*)d_in[8];
    const float* b2  = (const float*)d_in[9];
    const float* wc  = (const float*)d_in[10];
    const float* bc  = (const float*)d_in[11];
    float* out = (float*)d_out;

    char* p = (char*)d_ws;
    auto alloc = [&](size_t bytes) -> void* {
        void* r = (void*)p;
        p += (bytes + 255) & ~(size_t)255;
        return r;
    };
    float* h     = (float*)alloc((size_t)Nn * HCc * 4);
    float* t1    = (float*)alloc((size_t)Nn * HCc * 4);
    ushort_t* hb = (ushort_t*)alloc((size_t)Nn * HCc * 2);  // bf16 gather copy
    float* asv   = (float*)alloc((size_t)Nn * NH * 4);
    float* adv   = (float*)alloc((size_t)Nn * NH * 4);
    int* off     = (int*)alloc((Nn + 1) * 4);
    int* deg     = (int*)alloc(Nn * 4);
    int* cursor  = (int*)alloc(Nn * 4);
    int* bsum    = (int*)alloc(NCH * 4);
    int* boff    = (int*)alloc(NCH * 4);
    int* srcl    = (int*)alloc((size_t)(Ee + Nn) * 4);
    int* flag    = (int*)alloc(4);
    ushort_t* w1th = (ushort_t*)alloc((size_t)FIN * HCc * 2);
    ushort_t* w1tl = (ushort_t*)alloc((size_t)FIN * HCc * 2);
    ushort_t* w2th = (ushort_t*)alloc((size_t)HCc * HCc * 2);
    ushort_t* w2tl = (ushort_t*)alloc((size_t)HCc * HCc * 2);

    hipMemsetAsync(flag, 0, 4, stream);
    detect_idx_kernel<<<8, 256, 0, stream>>>((const unsigned int*)ei, flag);
    init_deg_kernel<<<(Nn + 255) / 256, 256, 0, stream>>>(deg);
    deg_count_kernel<<<(Ee + 255) / 256, 256, 0, stream>>>(ei, flag, deg);
    scan_k1<<<NCH, 256, 0, stream>>>(deg, off, bsum);
    scan_k2<<<1, 256, 0, stream>>>(bsum, boff);
    scan_k3<<<NCH, 256, 0, stream>>>(off, boff);
    cursor_init_kernel<<<(Nn + 255) / 256, 256, 0, stream>>>(off, cursor, srcl);
    fill_kernel<<<(Ee + 255) / 256, 256, 0, stream>>>(ei, flag, cursor, srcl);
    wsplit_kernel<<<(FIN * HCc + 255) / 256, 256, 0, stream>>>(w1, FIN, w1th, w1tl);
    wsplit_kernel<<<(HCc * HCc + 255) / 256, 256, 0, stream>>>(w2, HCc, w2th, w2tl);

    // layer 1
    gemm_mfma_kernel<<<dim3(2, (Nn + GBM - 1) / GBM), 256, 0, stream>>>(x, w1th, w1tl, h, hb, Nn, FIN);
    att_kernel<<<(Nn * NH + 255) / 256, 256, 0, stream>>>(h, as1, ad1, asv, adv);
    aggregate_kernel<<<(Nn + 3) / 4, 256, 0, stream>>>(hb, asv, adv, off, srcl, b1, t1, 1);
    // layer 2
    gemm_mfma_kernel<<<dim3(2, (Nn + GBM - 1) / GBM), 256, 0, stream>>>(t1, w2th, w2tl, h, hb, Nn, HCc);
    att_kernel<<<(Nn * NH + 255) / 256, 256, 0, stream>>>(h, as2, ad2, asv, adv);
    aggregate_kernel<<<(Nn + 3) / 4, 256, 0, stream>>>(hb, asv, adv, off, srcl, b2, t1, 0);
    // classifier
    classifier_kernel<<<(Nn + 31) / 32, 256, 0, stream>>>(t1, wc, bc, out);
}

// Round 12
// 467.184 us; speedup vs baseline: 1.3102x; 1.0627x over previous
//
#include <hip/hip_runtime.h>
#include <hip/hip_bf16.h>

#define Nn 50000
#define Ee 800000
#define FIN 128
#define HCc 256
#define NH 8
#define HIDc 32
#define NCLS 40
#define NCH ((Nn + 255) / 256)

typedef short s16x8 __attribute__((ext_vector_type(8)));
typedef unsigned short u16x8 __attribute__((ext_vector_type(8)));
typedef unsigned short u16x4 __attribute__((ext_vector_type(4)));
typedef float f32x4 __attribute__((ext_vector_type(4)));
typedef unsigned short ushort_t;

__device__ __forceinline__ ushort_t f2bf(float f) {
    unsigned u = __float_as_uint(f);
    unsigned r = (u + 0x7fffu + ((u >> 16) & 1u)) >> 16;
    return (ushort_t)r;
}
__device__ __forceinline__ float bf2f(ushort_t h) {
    return __uint_as_float(((unsigned)h) << 16);
}

// ---------------- index-width detection (int32 vs int64 edge_index) --------
__global__ void detect_idx_kernel(const unsigned int* __restrict__ ei, int* __restrict__ flag) {
    int t = blockIdx.x * blockDim.x + threadIdx.x;
    if (t < 2048) {
        if (ei[2 * t + 1] != 0u) atomicOr(flag, 1);  // nonzero odd word => int32 data
    }
}

__device__ __forceinline__ int load_idx(const void* ei, long long pos, int is32) {
    return is32 ? ((const int*)ei)[pos] : (int)((const long long*)ei)[pos];
}

// ---------------- CSR build ------------------------------------------------
__global__ void init_deg_kernel(int* __restrict__ deg) {
    int n = blockIdx.x * blockDim.x + threadIdx.x;
    if (n < Nn) deg[n] = 1;  // self loop
}

__global__ void deg_count_kernel(const void* __restrict__ ei, const int* __restrict__ flag,
                                 int* __restrict__ deg) {
    int e = blockIdx.x * blockDim.x + threadIdx.x;
    if (e >= Ee) return;
    int is32 = *flag;
    int d = load_idx(ei, (long long)Ee + e, is32);
    atomicAdd(&deg[d], 1);
}

__global__ __launch_bounds__(256) void scan_k1(const int* __restrict__ deg, int* __restrict__ off,
                                               int* __restrict__ bsum) {
    __shared__ int buf[256];
    int tid = threadIdx.x;
    int idx = blockIdx.x * 256 + tid;
    int v = (idx < Nn) ? deg[idx] : 0;
    buf[tid] = v;
    __syncthreads();
    for (int s = 1; s < 256; s <<= 1) {
        int t = (tid >= s) ? buf[tid - s] : 0;
        __syncthreads();
        buf[tid] += t;
        __syncthreads();
    }
    if (idx < Nn) off[idx + 1] = buf[tid];  // local inclusive; fixed in k3
    if (tid == 255) bsum[blockIdx.x] = buf[255];
}

__global__ __launch_bounds__(256) void scan_k2(const int* __restrict__ bsum, int* __restrict__ boff) {
    __shared__ int buf[256];
    int tid = threadIdx.x;
    int v = (tid < NCH) ? bsum[tid] : 0;
    buf[tid] = v;
    __syncthreads();
    for (int s = 1; s < 256; s <<= 1) {
        int t = (tid >= s) ? buf[tid - s] : 0;
        __syncthreads();
        buf[tid] += t;
        __syncthreads();
    }
    if (tid < NCH) boff[tid] = buf[tid] - v;  // exclusive
}

__global__ void scan_k3(int* __restrict__ off, const int* __restrict__ boff) {
    int idx = blockIdx.x * 256 + threadIdx.x;
    if (idx < Nn) off[idx + 1] += boff[blockIdx.x];
    if (idx == 0) off[0] = 0;
}

__global__ void cursor_init_kernel(const int* __restrict__ off, int* __restrict__ cursor,
                                   int* __restrict__ srcl) {
    int n = blockIdx.x * blockDim.x + threadIdx.x;
    if (n < Nn) {
        int b = off[n];
        srcl[b] = n;        // self loop occupies slot 0
        cursor[n] = b + 1;
    }
}

__global__ void fill_kernel(const void* __restrict__ ei, const int* __restrict__ flag,
                            int* __restrict__ cursor, int* __restrict__ srcl) {
    int e = blockIdx.x * blockDim.x + threadIdx.x;
    if (e >= Ee) return;
    int is32 = *flag;
    int s = load_idx(ei, e, is32);
    int d = load_idx(ei, (long long)Ee + e, is32);
    int slot = atomicAdd(&cursor[d], 1);
    srcl[slot] = s;
}

// ---------------- weight split+transpose: W[K,256] -> Wt_hi/lo[256,K] ------
__global__ void wsplit_kernel(const float* __restrict__ W, int K, ushort_t* __restrict__ Th,
                              ushort_t* __restrict__ Tl) {
    int idx = blockIdx.x * 256 + threadIdx.x;
    if (idx >= K * 256) return;
    int k = idx >> 8, n = idx & 255;
    float v = W[idx];
    ushort_t h = f2bf(v);
    ushort_t l = f2bf(v - bf2f(h));
    Th[n * K + k] = h;
    Tl[n * K + k] = l;
}

// ---------------- split-bf16 MFMA GEMM + fused attention scalars -----------
// C[M,256] = A[M,K] @ B[K,256]; output stored ONLY as bf16 (Cb, gather
// operand) -- no fp32 C. a_s/a_d dot products computed in-epilogue:
// each wave's 64x64 tile spans 2 complete heads (32 cols) for 64 rows ->
// in-wave shfl_xor reduction over the 16-lane column group, lane 0 writes.
#define GBM 128
#define GBN 128
#define GBK 64

__global__ __launch_bounds__(256) void gemm_mfma_kernel(
    const float* __restrict__ A, const ushort_t* __restrict__ BtH,
    const ushort_t* __restrict__ BtL, ushort_t* __restrict__ Cb,
    const float* __restrict__ att_s, const float* __restrict__ att_d,
    float* __restrict__ asv, float* __restrict__ adv, int M, int K) {
    __shared__ __align__(16) ushort_t AhS[GBM * GBK];
    __shared__ __align__(16) ushort_t AlS[GBM * GBK];
    __shared__ __align__(16) ushort_t BhS[GBN * GBK];
    __shared__ __align__(16) ushort_t BlS[GBN * GBK];
    int tid = threadIdx.x;
    int lane = tid & 63, wid = tid >> 6;
    int wm = wid >> 1, wn = wid & 1;  // 2x2 wave grid, each wave: 64x64 output
    int row0 = blockIdx.y * GBM, col0 = blockIdx.x * GBN;
    f32x4 acc[4][4] = {};
    for (int k0 = 0; k0 < K; k0 += GBK) {
        // stage A: fp32 -> (hi,lo) bf16, XOR-swizzled
        #pragma unroll
        for (int i = 0; i < 8; i++) {
            int q = tid + i * 256;
            int r = q >> 4, c4 = (q & 15) * 4;
            float4 v = make_float4(0.f, 0.f, 0.f, 0.f);
            int gr = row0 + r;
            if (gr < M) v = *(const float4*)(A + (size_t)gr * K + k0 + c4);
            ushort_t h0 = f2bf(v.x), h1 = f2bf(v.y), h2 = f2bf(v.z), h3 = f2bf(v.w);
            u16x4 hv = {h0, h1, h2, h3};
            u16x4 lv = {f2bf(v.x - bf2f(h0)), f2bf(v.y - bf2f(h1)), f2bf(v.z - bf2f(h2)),
                        f2bf(v.w - bf2f(h3))};
            int idx = (r * GBK + c4) ^ ((r & 7) << 3);
            *(u16x4*)&AhS[idx] = hv;
            *(u16x4*)&AlS[idx] = lv;
        }
        // stage B: pre-split bf16, 16B loads, XOR-swizzled
        #pragma unroll
        for (int i = 0; i < 4; i++) {
            int q = tid + i * 256;
            int r = q >> 3, c8 = (q & 7) * 8;
            size_t gofs = (size_t)(col0 + r) * K + k0 + c8;
            int idx = (r * GBK + c8) ^ ((r & 7) << 3);
            *(u16x8*)&BhS[idx] = *(const u16x8*)(BtH + gofs);
            *(u16x8*)&BlS[idx] = *(const u16x8*)(BtL + gofs);
        }
        __syncthreads();
        #pragma unroll
        for (int kk = 0; kk < GBK; kk += 32) {
            s16x8 ah[4], al[4], bh[4], bl[4];
            int kb = kk + (lane >> 4) * 8;
            #pragma unroll
            for (int f = 0; f < 4; f++) {
                int ra = wm * 64 + f * 16 + (lane & 15);
                int ia = (ra * GBK + kb) ^ ((ra & 7) << 3);
                ah[f] = *(const s16x8*)&AhS[ia];
                al[f] = *(const s16x8*)&AlS[ia];
                int rb = wn * 64 + f * 16 + (lane & 15);
                int ib = (rb * GBK + kb) ^ ((rb & 7) << 3);
                bh[f] = *(const s16x8*)&BhS[ib];
                bl[f] = *(const s16x8*)&BlS[ib];
            }
            #pragma unroll
            for (int fm = 0; fm < 4; fm++)
                #pragma unroll
                for (int fn = 0; fn < 4; fn++) {
                    acc[fm][fn] =
                        __builtin_amdgcn_mfma_f32_16x16x32_bf16(ah[fm], bh[fn], acc[fm][fn], 0, 0, 0);
                    acc[fm][fn] =
                        __builtin_amdgcn_mfma_f32_16x16x32_bf16(ah[fm], bl[fn], acc[fm][fn], 0, 0, 0);
                    acc[fm][fn] =
                        __builtin_amdgcn_mfma_f32_16x16x32_bf16(al[fm], bh[fn], acc[fm][fn], 0, 0, 0);
                }
        }
        __syncthreads();
    }
    // ---- epilogue ----
    // C/D layout: col = wn*64 + fn*16 + (lane&15), row = wm*64 + fm*16 + (lane>>4)*4 + j.
    // Wave heads: cols wn*64+{0..31} -> headA (fn 0,1); +{32..63} -> headB (fn 2,3).
    int lx = lane & 15;
    int headA = (col0 >> 5) + wn * 2;
    int headB = headA + 1;
    float sA0 = att_s[headA * HIDc + lx],      sA1 = att_s[headA * HIDc + 16 + lx];
    float sB0 = att_s[headB * HIDc + lx],      sB1 = att_s[headB * HIDc + 16 + lx];
    float dA0 = att_d[headA * HIDc + lx],      dA1 = att_d[headA * HIDc + 16 + lx];
    float dB0 = att_d[headB * HIDc + lx],      dB1 = att_d[headB * HIDc + 16 + lx];
    #pragma unroll
    for (int fm = 0; fm < 4; fm++) {
        int rbase = row0 + wm * 64 + fm * 16 + (lane >> 4) * 4;
        #pragma unroll
        for (int j = 0; j < 4; j++) {
            int gr = rbase + j;
            // bf16 shadow write (4 cols per lane via fn loop)
            #pragma unroll
            for (int fn = 0; fn < 4; fn++) {
                int c = col0 + wn * 64 + fn * 16 + lx;
                if (gr < M) Cb[(size_t)gr * HCc + c] = f2bf(acc[fm][fn][j]);
            }
            // fused a_s/a_d partial + 16-lane reduce
            float aA = acc[fm][0][j] * sA0 + acc[fm][1][j] * sA1;
            float dA = acc[fm][0][j] * dA0 + acc[fm][1][j] * dA1;
            float aB = acc[fm][2][j] * sB0 + acc[fm][3][j] * sB1;
            float dB = acc[fm][2][j] * dB0 + acc[fm][3][j] * dB1;
            #pragma unroll
            for (int o = 1; o < 16; o <<= 1) {
                aA += __shfl_xor(aA, o);
                dA += __shfl_xor(dA, o);
                aB += __shfl_xor(aB, o);
                dB += __shfl_xor(dB, o);
            }
            if (gr < M && lx == 0) {
                asv[gr * NH + headA] = aA;
                adv[gr * NH + headA] = dA;
                asv[gr * NH + headB] = aB;
                adv[gr * NH + headB] = dB;
            }
        }
    }
}

// ---------------- per-dst-node softmax + weighted aggregation --------------
// one wave per dst node; no max pass (softmax shift-invariant, |e|<~10 here).
// Gather operand is bf16 (hb): halves L2-miss-path bytes (the measured
// bottleneck: ~3.5-3.9 TB/s on random rows, R4/R9/R11). Accumulate fp32.
__global__ __launch_bounds__(256) void aggregate_kernel(
    const ushort_t* __restrict__ hb, const float* __restrict__ asv, const float* __restrict__ adv,
    const int* __restrict__ off, const int* __restrict__ srcl, const float* __restrict__ bias,
    float* __restrict__ out, int elu) {
    __shared__ float wbuf[4][512];  // 4 waves x 64 edges x 8 heads
    __shared__ int sbuf[4][64];     // 4 waves x 64 src indices
    int wave = threadIdx.x >> 6;
    int lane = threadIdx.x & 63;
    int n = blockIdx.x * 4 + wave;
    if (n >= Nn) return;
    int base = off[n];
    int deg = off[n + 1] - base;
    int ha = lane & 7;
    float adha = adv[n * NH + ha];
    float* wb = wbuf[wave];
    int* si = sbuf[wave];
    float ssum = 0.f;
    bool fast = (deg <= 64);
    if (fast) {
        if (lane < deg) si[lane] = srcl[base + lane];
        for (int p = lane; p < deg * NH; p += 64) {
            int s = si[p >> 3];
            float e = asv[s * NH + ha] + adha;
            e = (e >= 0.f) ? e : 0.2f * e;
            float ex = __expf(e);
            wb[p] = ex;
            ssum += ex;
        }
    } else {
        for (int p = lane; p < deg * NH; p += 64) {
            int s = srcl[base + (p >> 3)];
            float e = asv[s * NH + ha] + adha;
            e = (e >= 0.f) ? e : 0.2f * e;
            ssum += __expf(e);
        }
    }
    #pragma unroll
    for (int d = 8; d < 64; d <<= 1) ssum += __shfl_xor(ssum, d);
    float inv = 1.f / (ssum + 1e-16f);
    int hc = lane >> 3;
    float invc = __shfl(inv, hc);
    float4 acc = make_float4(0.f, 0.f, 0.f, 0.f);
    if (fast) {
        int i = 0;
        for (; i + 4 <= deg; i += 4) {
            int s0 = si[i + 0], s1 = si[i + 1], s2 = si[i + 2], s3 = si[i + 3];
            u16x4 b0 = *(const u16x4*)(hb + (size_t)s0 * HCc + lane * 4);
            u16x4 b1 = *(const u16x4*)(hb + (size_t)s1 * HCc + lane * 4);
            u16x4 b2 = *(const u16x4*)(hb + (size_t)s2 * HCc + lane * 4);
            u16x4 b3 = *(const u16x4*)(hb + (size_t)s3 * HCc + lane * 4);
            float w0 = wb[(i + 0) * NH + hc] * invc;
            float w1 = wb[(i + 1) * NH + hc] * invc;
            float w2 = wb[(i + 2) * NH + hc] * invc;
            float w3 = wb[(i + 3) * NH + hc] * invc;
            acc.x += w0 * bf2f(b0[0]) + w1 * bf2f(b1[0]) + w2 * bf2f(b2[0]) + w3 * bf2f(b3[0]);
            acc.y += w0 * bf2f(b0[1]) + w1 * bf2f(b1[1]) + w2 * bf2f(b2[1]) + w3 * bf2f(b3[1]);
            acc.z += w0 * bf2f(b0[2]) + w1 * bf2f(b1[2]) + w2 * bf2f(b2[2]) + w3 * bf2f(b3[2]);
            acc.w += w0 * bf2f(b0[3]) + w1 * bf2f(b1[3]) + w2 * bf2f(b2[3]) + w3 * bf2f(b3[3]);
        }
        for (; i < deg; i++) {
            int s = si[i];
            float w = wb[i * NH + hc] * invc;
            u16x4 bv4 = *(const u16x4*)(hb + (size_t)s * HCc + lane * 4);
            acc.x += w * bf2f(bv4[0]);
            acc.y += w * bf2f(bv4[1]);
            acc.z += w * bf2f(bv4[2]);
            acc.w += w * bf2f(bv4[3]);
        }
    } else {
        float adhc = adv[n * NH + hc];
        for (int i = 0; i < deg; i++) {
            int s = srcl[base + i];
            float e = asv[s * NH + hc] + adhc;
            e = (e >= 0.f) ? e : 0.2f * e;
            float w = __expf(e) * invc;
            u16x4 bv4 = *(const u16x4*)(hb + (size_t)s * HCc + lane * 4);
            acc.x += w * bf2f(bv4[0]);
            acc.y += w * bf2f(bv4[1]);
            acc.z += w * bf2f(bv4[2]);
            acc.w += w * bf2f(bv4[3]);
        }
    }
    float4 bv = *(const float4*)(bias + lane * 4);
    acc.x += bv.x;
    acc.y += bv.y;
    acc.z += bv.z;
    acc.w += bv.w;
    if (elu) {
        acc.x = (acc.x > 0.f) ? acc.x : expm1f(acc.x);
        acc.y = (acc.y > 0.f) ? acc.y : expm1f(acc.y);
        acc.z = (acc.z > 0.f) ? acc.z : expm1f(acc.z);
        acc.w = (acc.w > 0.f) ? acc.w : expm1f(acc.w);
    }
    *(float4*)(out + (size_t)n * HCc + lane * 4) = acc;
}

// ---------------- classifier: out[N,40] = h[N,256] @ wc[256,40] + bc -------
__global__ __launch_bounds__(256) void classifier_kernel(const float* __restrict__ h,
                                                         const float* __restrict__ wc,
                                                         const float* __restrict__ bc,
                                                         float* __restrict__ out) {
    __shared__ float hs[32][260];
    __shared__ float wcs[HCc * NCLS];
    int tid = threadIdx.x;
    int row0 = blockIdx.x * 32;
    #pragma unroll
    for (int i = 0; i < 8; i++) {
        int f = tid + i * 256;
        int r = f >> 6, c = (f & 63) * 4;
        float4 v = make_float4(0.f, 0.f, 0.f, 0.f);
        int gr = row0 + r;
        if (gr < Nn) v = *(const float4*)(h + (size_t)gr * HCc + c);
        *(float4*)&hs[r][c] = v;
    }
    #pragma unroll
    for (int i = 0; i < 10; i++) {
        int f = (tid + i * 256) * 4;
        *(float4*)&wcs[f] = *(const float4*)(wc + f);
    }
    __syncthreads();
    int r = tid >> 3, cg = tid & 7;
    int gr = row0 + r;
    if (gr >= Nn) return;
    float acc[5] = {0.f, 0.f, 0.f, 0.f, 0.f};
    for (int k = 0; k < HCc; k++) {
        float hv = hs[r][k];
        const float* w = &wcs[k * NCLS + cg * 5];
        #pragma unroll
        for (int j = 0; j < 5; j++) acc[j] += hv * w[j];
    }
    #pragma unroll
    for (int j = 0; j < 5; j++) out[(size_t)gr * NCLS + cg * 5 + j] = acc[j] + bc[cg * 5 + j];
}

// ---------------- launch ---------------------------------------------------
extern "C" void kernel_launch(void* const* d_in, const int* in_sizes, int n_in, void* d_out,
                              int out_size, void* d_ws, size_t ws_size, hipStream_t stream) {
    const float* x   = (const float*)d_in[0];
    const void*  ei  = d_in[1];
    const float* w1  = (const float*)d_in[2];
    const float* as1 = (const float*)d_in[3];
    const float* ad1 = (const float*)d_in[4];
    const float* b1  = (const float*)d_in[5];
    const float* w2  = (const float*)d_in[6];
    const float* as2 = (const float*)d_in[7];
    const float* ad2 = (const float*)d_in[8];
    const float* b2  = (const float*)d_in[9];
    const float* wc  = (const float*)d_in[10];
    const float* bc  = (const float*)d_in[11];
    float* out = (float*)d_out;

    char* p = (char*)d_ws;
    auto alloc = [&](size_t bytes) -> void* {
        void* r = (void*)p;
        p += (bytes + 255) & ~(size_t)255;
        return r;
    };
    float* t1    = (float*)alloc((size_t)Nn * HCc * 4);
    ushort_t* hb = (ushort_t*)alloc((size_t)Nn * HCc * 2);  // bf16 gather copy
    float* asv   = (float*)alloc((size_t)Nn * NH * 4);
    float* adv   = (float*)alloc((size_t)Nn * NH * 4);
    int* off     = (int*)alloc((Nn + 1) * 4);
    int* deg     = (int*)alloc(Nn * 4);
    int* cursor  = (int*)alloc(Nn * 4);
    int* bsum    = (int*)alloc(NCH * 4);
    int* boff    = (int*)alloc(NCH * 4);
    int* srcl    = (int*)alloc((size_t)(Ee + Nn) * 4);
    int* flag    = (int*)alloc(4);
    ushort_t* w1th = (ushort_t*)alloc((size_t)FIN * HCc * 2);
    ushort_t* w1tl = (ushort_t*)alloc((size_t)FIN * HCc * 2);
    ushort_t* w2th = (ushort_t*)alloc((size_t)HCc * HCc * 2);
    ushort_t* w2tl = (ushort_t*)alloc((size_t)HCc * HCc * 2);

    hipMemsetAsync(flag, 0, 4, stream);
    detect_idx_kernel<<<8, 256, 0, stream>>>((const unsigned int*)ei, flag);
    init_deg_kernel<<<(Nn + 255) / 256, 256, 0, stream>>>(deg);
    deg_count_kernel<<<(Ee + 255) / 256, 256, 0, stream>>>(ei, flag, deg);
    scan_k1<<<NCH, 256, 0, stream>>>(deg, off, bsum);
    scan_k2<<<1, 256, 0, stream>>>(bsum, boff);
    scan_k3<<<NCH, 256, 0, stream>>>(off, boff);
    cursor_init_kernel<<<(Nn + 255) / 256, 256, 0, stream>>>(off, cursor, srcl);
    fill_kernel<<<(Ee + 255) / 256, 256, 0, stream>>>(ei, flag, cursor, srcl);
    wsplit_kernel<<<(FIN * HCc + 255) / 256, 256, 0, stream>>>(w1, FIN, w1th, w1tl);
    wsplit_kernel<<<(HCc * HCc + 255) / 256, 256, 0, stream>>>(w2, HCc, w2th, w2tl);

    // layer 1 (gemm writes hb + asv/adv directly; no fp32 h, no att kernel)
    gemm_mfma_kernel<<<dim3(2, (Nn + GBM - 1) / GBM), 256, 0, stream>>>(
        x, w1th, w1tl, hb, as1, ad1, asv, adv, Nn, FIN);
    aggregate_kernel<<<(Nn + 3) / 4, 256, 0, stream>>>(hb, asv, adv, off, srcl, b1, t1, 1);
    // layer 2
    gemm_mfma_kernel<<<dim3(2, (Nn + GBM - 1) / GBM), 256, 0, stream>>>(
        t1, w2th, w2tl, hb, as2, ad2, asv, adv, Nn, HCc);
    aggregate_kernel<<<(Nn + 3) / 4, 256, 0, stream>>>(hb, asv, adv, off, srcl, b2, t1, 0);
    // classifier
    classifier_kernel<<<(Nn + 31) / 32, 256, 0, stream>>>(t1, wc, bc, out);
}